// Round 1
// baseline (183.664 us; speedup 1.0000x reference)
//
#include <hip/hip_runtime.h>

#define NN 50000
#define NE 100000
#define IN_F 63
#define HID 64
#define NREL 8
#define CHUNK 128

// ---------------- degree kernel: float histograms of senders/receivers ----
__global__ __launch_bounds__(256) void deg_kernel(const int* __restrict__ senders,
                                                  const int* __restrict__ receivers,
                                                  float* __restrict__ sdeg,
                                                  float* __restrict__ rdeg) {
    int e = blockIdx.x * 256 + threadIdx.x;
    if (e < NE) {
        atomicAdd(&sdeg[senders[e]], 1.0f);
        atomicAdd(&rdeg[receivers[e]], 1.0f);
    }
}

// ---------------- edge kernel: wave = (chunk, relation) ----------------
// Lane f keeps K[t][0..62][f] in 63 VGPRs (loaded once per wave).
// Wave ballot-scans its 128-edge chunk for edges of its relation, then for
// each match: 16 uniform float4 loads of the sender row, 63 FMAs,
// one coalesced 256B atomicAdd burst into agg[receiver].
__global__ __launch_bounds__(256) void edge_kernel(const float* __restrict__ nodes,
                                                   const int* __restrict__ senders,
                                                   const int* __restrict__ receivers,
                                                   const int* __restrict__ etypes,
                                                   const float* __restrict__ kernels,
                                                   const float* __restrict__ sdeg,
                                                   float* __restrict__ agg) {
    const int lane = threadIdx.x & 63;
    const int widG = (blockIdx.x * 256 + threadIdx.x) >> 6;
    const int t = widG & (NREL - 1);
    const int base = (widG >> 3) * CHUNK;
    if (base >= NE) return;

    // load this wave's relation column into registers (static indexing only)
    float kcol[IN_F];
    const float* Kt = kernels + (size_t)t * IN_F * HID;
#pragma unroll
    for (int i = 0; i < IN_F; ++i) kcol[i] = Kt[i * HID + lane];

    const int lim = min(base + CHUNK, NE);
    for (int eb = base; eb < lim; eb += 64) {
        const int e = eb + lane;
        int ty = -1;
        if (e < lim) ty = etypes[e];
        unsigned long long m = __ballot(ty == t);
        while (m) {
            const int idx = __builtin_ctzll(m);
            m &= (m - 1);
            const int ee = eb + idx;                    // wave-uniform
            const int s = senders[ee];
            const int r = receivers[ee];
            const float4* x4 = (const float4*)(nodes + (size_t)s * (IN_F + 1));
            float acc = 0.f;
#pragma unroll
            for (int j = 0; j < 16; ++j) {
                float4 v = x4[j];
                acc = fmaf(kcol[4 * j + 0], v.x, acc);
                acc = fmaf(kcol[4 * j + 1], v.y, acc);
                acc = fmaf(kcol[4 * j + 2], v.z, acc);
                if (4 * j + 3 < IN_F)                   // skip is_root slot (elem 63)
                    acc = fmaf(kcol[4 * j + 3], v.w, acc);
            }
            const float ns = rsqrtf(fmaxf(sdeg[s], 1.0f));
            atomicAdd(&agg[(size_t)r * HID + lane], acc * ns);
        }
    }
}

// ---------------- readout: sum_n is_root[n] * relu(agg[n]*nr[n]) . w + b ---
__global__ __launch_bounds__(256) void readout_kernel(const float* __restrict__ nodes,
                                                      const float* __restrict__ agg,
                                                      const float* __restrict__ rdeg,
                                                      const float* __restrict__ w,
                                                      const float* __restrict__ b,
                                                      float* __restrict__ out) {
    __shared__ float bsum;
    if (threadIdx.x == 0) bsum = 0.f;
    __syncthreads();

    const int lane = threadIdx.x & 63;
    const int gw = blockIdx.x * 4 + (threadIdx.x >> 6);
    const int nw = gridDim.x * 4;
    const float wf = w[lane];

    float local = 0.f;  // lane f accumulates sum_n is_root[n]*relu(agg[n,f]*nr[n])
    for (int n = gw; n < NN; n += nw) {
        float a = agg[(size_t)n * HID + lane];
        float nr = rsqrtf(fmaxf(rdeg[n], 1.0f));
        float root = nodes[(size_t)n * (IN_F + 1) + IN_F];  // wave-uniform
        local += fmaxf(a * nr, 0.f) * root;
    }
    float v = local * wf;
#pragma unroll
    for (int o = 32; o > 0; o >>= 1) v += __shfl_xor(v, o, 64);

    if (lane == 0) atomicAdd(&bsum, v);
    __syncthreads();
    if (threadIdx.x == 0) {
        float val = bsum;
        if (blockIdx.x == 0) val += b[0];
        atomicAdd(out, val);
    }
}

extern "C" void kernel_launch(void* const* d_in, const int* in_sizes, int n_in,
                              void* d_out, int out_size, void* d_ws, size_t ws_size,
                              hipStream_t stream) {
    const float* nodes     = (const float*)d_in[0];
    const int*   senders   = (const int*)d_in[1];
    const int*   receivers = (const int*)d_in[2];
    const int*   etypes    = (const int*)d_in[3];
    // d_in[4] = n_node (single graph; unused)
    const float* kernels   = (const float*)d_in[5];
    const float* dense_w   = (const float*)d_in[6];
    const float* dense_b   = (const float*)d_in[7];
    float* out = (float*)d_out;

    float* agg  = (float*)d_ws;                 // NN x HID
    float* sdeg = agg + (size_t)NN * HID;       // NN
    float* rdeg = sdeg + NN;                    // NN

    size_t zero_bytes = ((size_t)NN * HID + 2 * (size_t)NN) * sizeof(float);
    hipMemsetAsync(d_ws, 0, zero_bytes, stream);
    hipMemsetAsync(d_out, 0, sizeof(float), stream);

    deg_kernel<<<(NE + 255) / 256, 256, 0, stream>>>(senders, receivers, sdeg, rdeg);

    const int nchunks = (NE + CHUNK - 1) / CHUNK;       // 782
    const int waves   = nchunks * NREL;                 // 6256
    const int blocks  = (waves * 64 + 255) / 256;       // 1564
    edge_kernel<<<blocks, 256, 0, stream>>>(nodes, senders, receivers, etypes,
                                            kernels, sdeg, agg);

    readout_kernel<<<848, 256, 0, stream>>>(nodes, agg, rdeg, dense_w, dense_b, out);
}

// Round 2
// 134.819 us; speedup vs baseline: 1.3623x; 1.3623x over previous
//
#include <hip/hip_runtime.h>

#define NN 50000
#define NE 100000
#define IN_F 63
#define HID 64
#define NREL 8
#define CHUNK 64

// ---------------- degree kernel: float histograms of senders/receivers ----
__global__ __launch_bounds__(256) void deg_kernel(const int* __restrict__ senders,
                                                  const int* __restrict__ receivers,
                                                  float* __restrict__ sdeg,
                                                  float* __restrict__ rdeg) {
    int e = blockIdx.x * 256 + threadIdx.x;
    if (e < NE) {
        atomicAdd(&sdeg[senders[e]], 1.0f);
        atomicAdd(&rdeg[receivers[e]], 1.0f);
    }
}

// ---------------- edge kernel ----------------
// Wave = (chunk of 64 edges, relation t). Lane f keeps K[t][0..62][f] in 63
// VGPRs. Lanes cooperatively preload edge metadata (+predicated sdeg gather,
// rsqrt) for the chunk; ballot picks matching edges; the serial loop handles
// TWO edges per iteration with 4 rotating accumulators each (8 indep FMA
// chains) and fires one coalesced 256B atomicAdd per edge.
// Block mapping: t = blockIdx&7 so all 4 waves of a block share the K panel
// (16KB -> L1 hits for waves 2..4).
__global__ __launch_bounds__(256, 4) void edge_kernel(const float* __restrict__ nodes,
                                                      const int* __restrict__ senders,
                                                      const int* __restrict__ receivers,
                                                      const int* __restrict__ etypes,
                                                      const float* __restrict__ kernels,
                                                      const float* __restrict__ sdeg,
                                                      float* __restrict__ agg) {
    const int lane = threadIdx.x & 63;
    const int t = blockIdx.x & (NREL - 1);
    const int chunk = (blockIdx.x >> 3) * 4 + (threadIdx.x >> 6);
    const int base = chunk * CHUNK;
    if (base >= NE) return;
    const int lim = min(base + CHUNK, NE);

    // this wave's relation column, held in registers for the whole kernel
    float kcol[IN_F];
    const float* Kt = kernels + (size_t)t * IN_F * HID;
#pragma unroll
    for (int i = 0; i < IN_F; ++i) kcol[i] = Kt[i * HID + lane];

    // cooperative preload of edge metadata for the 64-edge chunk
    const int e = base + lane;
    int s_l = 0, r_l = 0, ty = -1;
    if (e < lim) {
        ty  = etypes[e];
        s_l = senders[e];
        r_l = receivers[e];
    }
    float ns_l = 1.0f;
    if (ty == t) ns_l = rsqrtf(fmaxf(sdeg[s_l], 1.0f));  // predicated gather

    unsigned long long m = __ballot(ty == t);
    while (m) {
        const int i0 = __builtin_ctzll(m); m &= m - 1;
        const bool has2 = (m != 0);
        const int i1 = has2 ? __builtin_ctzll(m) : i0;
        if (has2) m &= m - 1;

        const int   s0  = __builtin_amdgcn_readfirstlane(__shfl(s_l, i0));
        const int   r0  = __builtin_amdgcn_readfirstlane(__shfl(r_l, i0));
        const float ns0 = __shfl(ns_l, i0);
        const int   s1  = __builtin_amdgcn_readfirstlane(__shfl(s_l, i1));
        const int   r1  = __builtin_amdgcn_readfirstlane(__shfl(r_l, i1));
        const float ns1 = __shfl(ns_l, i1);

        const float4* xa = (const float4*)(nodes + (size_t)s0 * (IN_F + 1));
        const float4* xb = (const float4*)(nodes + (size_t)s1 * (IN_F + 1));
        float a0 = 0.f, a1 = 0.f, a2 = 0.f, a3 = 0.f;
        float b0 = 0.f, b1 = 0.f, b2 = 0.f, b3 = 0.f;
#pragma unroll
        for (int j = 0; j < 16; ++j) {
            const float4 va = xa[j];
            const float4 vb = xb[j];
            a0 = fmaf(kcol[4 * j + 0], va.x, a0);
            a1 = fmaf(kcol[4 * j + 1], va.y, a1);
            a2 = fmaf(kcol[4 * j + 2], va.z, a2);
            if (4 * j + 3 < IN_F) a3 = fmaf(kcol[4 * j + 3], va.w, a3);
            b0 = fmaf(kcol[4 * j + 0], vb.x, b0);
            b1 = fmaf(kcol[4 * j + 1], vb.y, b1);
            b2 = fmaf(kcol[4 * j + 2], vb.z, b2);
            if (4 * j + 3 < IN_F) b3 = fmaf(kcol[4 * j + 3], vb.w, b3);
        }
        atomicAdd(&agg[(size_t)r0 * HID + lane], ((a0 + a1) + (a2 + a3)) * ns0);
        if (has2)
            atomicAdd(&agg[(size_t)r1 * HID + lane], ((b0 + b1) + (b2 + b3)) * ns1);
    }
}

// ---------------- readout: sum_n is_root[n] * relu(agg[n]*nr[n]) . w + b ---
__global__ __launch_bounds__(256) void readout_kernel(const float* __restrict__ nodes,
                                                      const float* __restrict__ agg,
                                                      const float* __restrict__ rdeg,
                                                      const float* __restrict__ w,
                                                      const float* __restrict__ b,
                                                      float* __restrict__ out) {
    __shared__ float bsum;
    if (threadIdx.x == 0) bsum = 0.f;
    __syncthreads();

    const int lane = threadIdx.x & 63;
    const int gw = blockIdx.x * 4 + (threadIdx.x >> 6);
    const int nw = gridDim.x * 4;
    const float wf = w[lane];

    float local = 0.f;  // lane f accumulates sum_n is_root[n]*relu(agg[n,f]*nr[n])
    for (int n = gw; n < NN; n += nw) {
        float a = agg[(size_t)n * HID + lane];
        float nr = rsqrtf(fmaxf(rdeg[n], 1.0f));
        float root = nodes[(size_t)n * (IN_F + 1) + IN_F];  // wave-uniform
        local += fmaxf(a * nr, 0.f) * root;
    }
    float v = local * wf;
#pragma unroll
    for (int o = 32; o > 0; o >>= 1) v += __shfl_xor(v, o, 64);

    if (lane == 0) atomicAdd(&bsum, v);
    __syncthreads();
    if (threadIdx.x == 0) {
        float val = bsum;
        if (blockIdx.x == 0) val += b[0];
        atomicAdd(out, val);
    }
}

extern "C" void kernel_launch(void* const* d_in, const int* in_sizes, int n_in,
                              void* d_out, int out_size, void* d_ws, size_t ws_size,
                              hipStream_t stream) {
    const float* nodes     = (const float*)d_in[0];
    const int*   senders   = (const int*)d_in[1];
    const int*   receivers = (const int*)d_in[2];
    const int*   etypes    = (const int*)d_in[3];
    // d_in[4] = n_node (single graph; unused)
    const float* kernels   = (const float*)d_in[5];
    const float* dense_w   = (const float*)d_in[6];
    const float* dense_b   = (const float*)d_in[7];
    float* out = (float*)d_out;

    float* agg  = (float*)d_ws;                 // NN x HID
    float* sdeg = agg + (size_t)NN * HID;       // NN
    float* rdeg = sdeg + NN;                    // NN

    size_t zero_bytes = ((size_t)NN * HID + 2 * (size_t)NN) * sizeof(float);
    hipMemsetAsync(d_ws, 0, zero_bytes, stream);
    hipMemsetAsync(d_out, 0, sizeof(float), stream);

    deg_kernel<<<(NE + 255) / 256, 256, 0, stream>>>(senders, receivers, sdeg, rdeg);

    const int nchunks = (NE + CHUNK - 1) / CHUNK;          // 1563
    const int cgroups = (nchunks + 3) / 4;                 // 391
    const int blocks  = cgroups * NREL;                    // 3128
    edge_kernel<<<blocks, 256, 0, stream>>>(nodes, senders, receivers, etypes,
                                            kernels, sdeg, agg);

    readout_kernel<<<1024, 256, 0, stream>>>(nodes, agg, rdeg, dense_w, dense_b, out);
}